// Round 9
// baseline (85.200 us; speedup 1.0000x reference)
//
#include <hip/hip_runtime.h>
#include <stdint.h>

#define ALPHA 0.2f
#define LOG2E 1.44269504089f

typedef __attribute__((ext_vector_type(8))) short s16x8;
typedef __attribute__((ext_vector_type(4))) float f32x4;
typedef __attribute__((ext_vector_type(4))) unsigned u32x4;

__device__ __forceinline__ unsigned short f2bf(float f) {
    union { float f; unsigned u; } c; c.f = f;
    unsigned u = c.u;
    u += 0x7fffu + ((u >> 16) & 1u);
    return (unsigned short)(u >> 16);
}

// ---- prep: wT bf16 [c=256][f=256] (c=(h,e)) + wa1/wa2 = log2e * W@a{1,2} ----
__global__ void k_prep_w(const float* __restrict__ weight, const float* __restrict__ att,
                         unsigned short* __restrict__ wT, float* __restrict__ wa1,
                         float* __restrict__ wa2) {
    int blk = blockIdx.x, t = threadIdx.x;
    if (blk < 256) {
        int c = blk, h = c >> 5, e = c & 31;
        wT[c * 256 + t] = f2bf(weight[h * 8192 + t * 32 + e]);
    } else {
        int id = blk - 256, h = id >> 1, which = id & 1;
        float s = 0.f;
        for (int e = 0; e < 32; ++e)
            s += weight[h * 8192 + t * 32 + e] * att[h * 64 + which * 32 + e];
        s *= LOG2E;   // scores in log2 domain (leaky commutes with positive scale)
        (which ? wa2 : wa1)[h * 256 + t] = s;
    }
}

// ---- adj -> packed bitmask (1MB) + x -> bf16 copy, both streaming ----
__global__ void k_mask(const int* __restrict__ adj, unsigned* __restrict__ gmask,
                       const float* __restrict__ x, unsigned short* __restrict__ x16) {
    int t = threadIdx.x, w = t >> 6, l = t & 63;
    int wid = blockIdx.x * 4 + w;
#pragma unroll
    for (int i = 0; i < 4; ++i) {
        int c = wid * 4 + i;
        int val = adj[c * 64 + l];
        unsigned long long mk = __ballot(val > 0);
        if (l == 0) {
            gmask[c * 2]     = (unsigned)mk;
            gmask[c * 2 + 1] = (unsigned)(mk >> 32);
        }
    }
    int idx = blockIdx.x * 256 + t;
    x16[idx] = f2bf(x[idx]);
}

// ---- s1,s2 fp32 exact-score path (s1 = x @ (W@a1)) ----
__global__ void k_prep_s(const float* __restrict__ x, const float* __restrict__ wa1,
                         const float* __restrict__ wa2, float* __restrict__ s1,
                         float* __restrict__ s2) {
    __shared__ float xs[256];
    int bm = blockIdx.x, t = threadIdx.x;
    xs[t] = x[bm * 256 + t];
    __syncthreads();
    int lane16 = t & 15, grp = t >> 4;
    int h = grp >> 1, which = grp & 1;
    const float* wap = (which ? wa2 : wa1) + h * 256;
    float s = 0.f;
    for (int f = lane16; f < 256; f += 16) s += xs[f] * wap[f];
    s += __shfl_xor(s, 8); s += __shfl_xor(s, 4);
    s += __shfl_xor(s, 2); s += __shfl_xor(s, 1);
    if (lane16 == 0) {
        int b = bm >> 10, m = bm & 1023;
        (which ? s2 : s1)[(b * 8 + h) * 1024 + m] = s;
    }
}

// ---- WhT[(b,h,e)][m] bf16 = (x@W)^T via MFMA; BM=32 tiles (4096 waves) ----
__global__ void k_wht(const unsigned short* __restrict__ wT,
                      const unsigned short* __restrict__ x16,
                      unsigned short* __restrict__ WhT) {
    int t = threadIdx.x;
    int W = blockIdx.x * 4 + (t >> 6);
    int l = t & 63;
    int b = W >> 9, r = W & 511;
    int c0 = (r >> 5) * 16, m0 = (r & 31) * 32;
    int lrow = l & 15, lk = l >> 4;
    f32x4 acc[2] = {{0,0,0,0},{0,0,0,0}};
    const unsigned short* ap = wT + (c0 + lrow) * 256 + lk * 8;
    const unsigned short* bp = x16 + (b * 1024 + m0 + lrow) * 256 + lk * 8;
    for (int k0 = 0; k0 < 256; k0 += 32) {
        s16x8 af = *(const s16x8*)(ap + k0);
#pragma unroll
        for (int t4 = 0; t4 < 2; ++t4) {
            s16x8 bf = *(const s16x8*)(bp + t4 * 16 * 256 + k0);
            acc[t4] = __builtin_amdgcn_mfma_f32_16x16x32_bf16(af, bf, acc[t4], 0, 0, 0);
        }
    }
#pragma unroll
    for (int t4 = 0; t4 < 2; ++t4)
#pragma unroll
        for (int j = 0; j < 4; ++j) {
            int c = c0 + lk * 4 + j;
            int m = m0 + t4 * 16 + lrow;
            WhT[(b * 256 + c) * 1024 + m] = f2bf(acc[t4][j]);
        }
}

// ---- attention: online one-pass softmax; 4 waves = 2 heads x 2 n-halves ----
__global__ void __launch_bounds__(256) k_attn(const unsigned* __restrict__ gmask,
                                              const float* __restrict__ s1,
                                              const float* __restrict__ s2,
                                              const unsigned short* __restrict__ WhT,
                                              float* __restrict__ out) {
    __shared__ float s2s[2][1024];
    __shared__ unsigned amaskw[16][33];
    __shared__ float s1s[2][16];
    __shared__ float accsh[2][64][14];   // 12 acc + 1 mr; stride 14 (even, !=32-mult)
    int bid = blockIdx.x;
    int o = (bid & 7) * 256 + (bid >> 3);   // XCD swizzle: each XCD owns one b
    int b = o >> 8, r = o & 255;
    int m0 = (r >> 2) * 16, hg = (r & 3) * 2;
    int t = threadIdx.x, w = t >> 6, l = t & 63;
    int hd = w & 1, nh = w >> 1;
    for (int i = t; i < 2048; i += 256) s2s[i >> 10][i & 1023] = s2[b * 8192 + hg * 1024 + i];
    for (int i = t; i < 512; i += 256) amaskw[i >> 5][i & 31] = gmask[(b * 1024 + m0) * 32 + i];
    if (t < 32) s1s[t >> 4][t & 15] = s1[b * 8192 + (hg + (t >> 4)) * 1024 + m0 + (t & 15)];
    __syncthreads();
    int m = l & 15, q = l >> 4;
    int h = hg + hd;
    float s1v = s1s[hd][m];
    float c2 = ALPHA * s1v;
    int nbase = nh * 512;
    float mr = -1.0e30f;                 // running masked row-max (log2-leaky domain)
    f32x4 acc0 = {0,0,0,0}, acc1 = {0,0,0,0}, accs = {0,0,0,0};
    s16x8 ones;
#pragma unroll
    for (int u = 0; u < 8; ++u) ones[u] = (short)0x3F80;   // bf16 1.0
    const unsigned short* whb = WhT + (b * 8 + h) * 32768;
    const unsigned short* bp0 = whb + m * 1024 + q * 8 + nbase;
    const unsigned short* bp1 = bp0 + 16 * 1024;
#pragma unroll 2
    for (int n0 = 0; n0 < 512; n0 += 32) {
        unsigned wm8 = amaskw[m][(nbase + n0) >> 5] >> (q * 8);
        int nn = nbase + n0 + q * 8;
        f32x4 svA = *(const f32x4*)&s2s[hd][nn];
        f32x4 svB = *(const f32x4*)&s2s[hd][nn + 4];
        float cand[8];
#pragma unroll
        for (int u = 0; u < 8; ++u) {
            float sv = (u < 4 ? svA[u] : svB[u - 4]);
            float a = sv + s1v;
            float bb = fmaf(ALPHA, sv, c2);
            float lkv = fmaxf(a, bb);                       // leaky(score), absolute
            cand[u] = ((wm8 >> u) & 1u) ? lkv : -3.0e38f;   // masked candidate
        }
        float tmax = fmaxf(fmaxf(fmaxf(cand[0], cand[1]), fmaxf(cand[2], cand[3])),
                           fmaxf(fmaxf(cand[4], cand[5]), fmaxf(cand[6], cand[7])));
        tmax = fmaxf(tmax, __shfl_xor(tmax, 16));
        tmax = fmaxf(tmax, __shfl_xor(tmax, 32));           // row tile-max
        if (__any(tmax > mr)) {                             // rare, wave-uniform
            float mnew = fmaxf(mr, tmax);
            float delta = mr - mnew;                        // <= 0
            mr = mnew;
#pragma unroll
            for (int j = 0; j < 4; ++j) {
                float fj = __builtin_amdgcn_exp2f(__shfl(delta, q * 4 + j));
                acc0[j] *= fj; acc1[j] *= fj; accs[j] *= fj;
            }
        }
        float pv[8];
#pragma unroll
        for (int u = 0; u < 8; ++u)
            pv[u] = __builtin_amdgcn_exp2f(cand[u] - mr);   // masked: -3e38-mr -> 0
        u32x4 aw;
#pragma unroll
        for (int p = 0; p < 4; ++p) {
            union { float f; unsigned u; } lo, hi;
            lo.f = pv[2 * p]; hi.f = pv[2 * p + 1];
            aw[p] = __builtin_amdgcn_perm(hi.u, lo.u, 0x07060302u);  // trunc-pack 2xbf16
        }
        s16x8 af = __builtin_bit_cast(s16x8, aw);
        s16x8 bf0 = *(const s16x8*)(bp0 + n0);
        s16x8 bf1 = *(const s16x8*)(bp1 + n0);
        acc0 = __builtin_amdgcn_mfma_f32_16x16x32_bf16(af, bf0, acc0, 0, 0, 0);
        acc1 = __builtin_amdgcn_mfma_f32_16x16x32_bf16(af, bf1, acc1, 0, 0, 0);
        accs = __builtin_amdgcn_mfma_f32_16x16x32_bf16(af, ones, accs, 0, 0, 0);
    }
    if (nh == 1) {
#pragma unroll
        for (int j = 0; j < 4; ++j) {
            accsh[hd][l][j]     = acc0[j];
            accsh[hd][l][4 + j] = acc1[j];
            accsh[hd][l][8 + j] = accs[j];
        }
        accsh[hd][l][12] = mr;
    }
    __syncthreads();
    if (nh == 0) {
#pragma unroll
        for (int j = 0; j < 4; ++j) {
            int mrow = q * 4 + j;
            float mr0 = __shfl(mr, mrow);                  // own half's max, row mrow
            float mr1 = accsh[hd][mrow][12];               // other half's max
            float M = fmaxf(mr0, mr1);
            float f0 = __builtin_amdgcn_exp2f(mr0 - M);
            float f1 = __builtin_amdgcn_exp2f(mr1 - M);
            float a0 = acc0[j] * f0 + accsh[hd][l][j]     * f1;
            float a1 = acc1[j] * f0 + accsh[hd][l][4 + j] * f1;
            float as = accs[j] * f0 + accsh[hd][l][8 + j] * f1;
            float inv = 1.f / as;
            float v0 = a0 * inv;
            float v1 = a1 * inv;
            v0 = v0 > 0.f ? v0 : __expf(v0) - 1.f;
            v1 = v1 > 0.f ? v1 : __expf(v1) - 1.f;
            float* op = &out[(b * 1024 + m0 + mrow) * 256 + h * 32];
            op[m] = v0;
            op[16 + m] = v1;
        }
    }
}

extern "C" void kernel_launch(void* const* d_in, const int* in_sizes, int n_in,
                              void* d_out, int out_size, void* d_ws, size_t ws_size,
                              hipStream_t stream) {
    const float* x      = (const float*)d_in[0];
    const int*   adj    = (const int*)d_in[1];
    const float* weight = (const float*)d_in[2];
    const float* att    = (const float*)d_in[3];

    char* ws = (char*)d_ws;
    unsigned short* wT  = (unsigned short*)(ws);             // 128K
    unsigned short* x16 = (unsigned short*)(ws + 131072);    // 4M
    unsigned short* WhT = (unsigned short*)(ws + 4325376);   // 4M
    float* s1  = (float*)(ws + 8519680);                     // 256K
    float* s2  = (float*)(ws + 8781824);                     // 256K
    float* wa1 = (float*)(ws + 9043968);                     // 8K
    float* wa2 = (float*)(ws + 9052160);                     // 8K
    unsigned* gmask = (unsigned*)(ws + 9060352);             // 1M
    float* out = (float*)d_out;

    k_prep_w<<<272, 256, 0, stream>>>(weight, att, wT, wa1, wa2);
    k_mask<<<8192, 256, 0, stream>>>(adj, gmask, x, x16);
    k_prep_s<<<8192, 256, 0, stream>>>(x, wa1, wa2, s1, s2);
    k_wht<<<1024, 256, 0, stream>>>(wT, x16, WhT);
    k_attn<<<2048, 256, 0, stream>>>(gmask, s1, s2, WhT, out);
}

// Round 11
// 82.516 us; speedup vs baseline: 1.0325x; 1.0325x over previous
//
#include <hip/hip_runtime.h>
#include <stdint.h>

#define ALPHA 0.2f
#define LOG2E 1.44269504089f

typedef __attribute__((ext_vector_type(8))) short s16x8;
typedef __attribute__((ext_vector_type(4))) float f32x4;
typedef __attribute__((ext_vector_type(4))) unsigned u32x4;

__device__ __forceinline__ unsigned short f2bf(float f) {
    union { float f; unsigned u; } c; c.f = f;
    unsigned u = c.u;
    u += 0x7fffu + ((u >> 16) & 1u);
    return (unsigned short)(u >> 16);
}

// ---- prep: wT bf16 [c=256][f=256] (c=(h,e)) + wa1/wa2 = log2e * W@a{1,2} ----
__global__ void k_prep_w(const float* __restrict__ weight, const float* __restrict__ att,
                         unsigned short* __restrict__ wT, float* __restrict__ wa1,
                         float* __restrict__ wa2) {
    int blk = blockIdx.x, t = threadIdx.x;
    if (blk < 256) {
        int c = blk, h = c >> 5, e = c & 31;
        wT[c * 256 + t] = f2bf(weight[h * 8192 + t * 32 + e]);
    } else {
        int id = blk - 256, h = id >> 1, which = id & 1;
        float s = 0.f;
        for (int e = 0; e < 32; ++e)
            s += weight[h * 8192 + t * 32 + e] * att[h * 64 + which * 32 + e];
        s *= LOG2E;   // scores in log2 domain (leaky commutes with positive scale)
        (which ? wa2 : wa1)[h * 256 + t] = s;
    }
}

// ---- fused: adj->bitmask, x->bf16, s1/s2 dot products (one streaming pass) ----
__global__ void __launch_bounds__(256) k_pre(const int* __restrict__ adj,
                                             unsigned* __restrict__ gmask,
                                             const float* __restrict__ x,
                                             unsigned short* __restrict__ x16,
                                             const float* __restrict__ wa1,
                                             const float* __restrict__ wa2,
                                             float* __restrict__ s1,
                                             float* __restrict__ s2) {
    __shared__ float xs[256];
    int blk = blockIdx.x, t = threadIdx.x, w = t >> 6, l = t & 63;
    float xv = x[blk * 256 + t];
    xs[t] = xv;
    x16[blk * 256 + t] = f2bf(xv);
    int wid = blk * 4 + w;
#pragma unroll
    for (int i = 0; i < 4; ++i) {
        int c = wid * 4 + i;
        int val = adj[c * 64 + l];
        unsigned long long mk = __ballot(val > 0);
        if (l == 0) {
            gmask[c * 2]     = (unsigned)mk;
            gmask[c * 2 + 1] = (unsigned)(mk >> 32);
        }
    }
    __syncthreads();
    int lane16 = t & 15, grp = t >> 4;
    int h = grp >> 1, which = grp & 1;
    const float* wap = (which ? wa2 : wa1) + h * 256;
    float s = 0.f;
    for (int f = lane16; f < 256; f += 16) s += xs[f] * wap[f];
    s += __shfl_xor(s, 8); s += __shfl_xor(s, 4);
    s += __shfl_xor(s, 2); s += __shfl_xor(s, 1);
    if (lane16 == 0) {
        int b = blk >> 10, m = blk & 1023;
        (which ? s2 : s1)[(b * 8 + h) * 1024 + m] = s;
    }
}

// ---- WhT[(b,h,e)][m] bf16 = (x@W)^T via MFMA; BM=32 tiles (4096 waves) ----
__global__ void k_wht(const unsigned short* __restrict__ wT,
                      const unsigned short* __restrict__ x16,
                      unsigned short* __restrict__ WhT) {
    int t = threadIdx.x;
    int W = blockIdx.x * 4 + (t >> 6);
    int l = t & 63;
    int b = W >> 9, r = W & 511;
    int c0 = (r >> 5) * 16, m0 = (r & 31) * 32;
    int lrow = l & 15, lk = l >> 4;
    f32x4 acc[2] = {{0,0,0,0},{0,0,0,0}};
    const unsigned short* ap = wT + (c0 + lrow) * 256 + lk * 8;
    const unsigned short* bp = x16 + (b * 1024 + m0 + lrow) * 256 + lk * 8;
    for (int k0 = 0; k0 < 256; k0 += 32) {
        s16x8 af = *(const s16x8*)(ap + k0);
#pragma unroll
        for (int t4 = 0; t4 < 2; ++t4) {
            s16x8 bf = *(const s16x8*)(bp + t4 * 16 * 256 + k0);
            acc[t4] = __builtin_amdgcn_mfma_f32_16x16x32_bf16(af, bf, acc[t4], 0, 0, 0);
        }
    }
#pragma unroll
    for (int t4 = 0; t4 < 2; ++t4)
#pragma unroll
        for (int j = 0; j < 4; ++j) {
            int c = c0 + lk * 4 + j;
            int m = m0 + t4 * 16 + lrow;
            WhT[(b * 256 + c) * 1024 + m] = f2bf(acc[t4][j]);
        }
}

// ---- attention: EXACT masked row-max (pass A, reg masks, 8 indep accums)
//      + unrolled pass B; halves share one mx via LDS exchange ----
__global__ void __launch_bounds__(256, 4) k_attn(const unsigned* __restrict__ gmask,
                                                 const float* __restrict__ s1,
                                                 const float* __restrict__ s2,
                                                 const unsigned short* __restrict__ WhT,
                                                 float* __restrict__ out) {
    __shared__ float s2s[2][1024];
    __shared__ unsigned amaskw[16][36];   // rows 144B: 16B-aligned, 2-way-free banks
    __shared__ float s1s[2][16];
    __shared__ float mxsh[2][16][2];
    __shared__ float accsh[2][64][13];
    int bid = blockIdx.x;
    int o = (bid & 7) * 256 + (bid >> 3);   // XCD swizzle: each XCD owns one b
    int b = o >> 8, r = o & 255;
    int m0 = (r >> 2) * 16, hg = (r & 3) * 2;
    int t = threadIdx.x, w = t >> 6, l = t & 63;
    int hd = w & 1, nh = w >> 1;
    for (int i = t; i < 2048; i += 256) s2s[i >> 10][i & 1023] = s2[b * 8192 + hg * 1024 + i];
    for (int i = t; i < 512; i += 256) amaskw[i >> 5][i & 31] = gmask[(b * 1024 + m0) * 32 + i];
    if (t < 32) s1s[t >> 4][t & 15] = s1[b * 8192 + (hg + (t >> 4)) * 1024 + m0 + (t & 15)];
    __syncthreads();
    int m = l & 15, q = l >> 4;
    int h = hg + hd;
    int nbase = nh * 512;
    u32x4 mv0 = *(const u32x4*)&amaskw[m][nh * 16];
    u32x4 mv1 = *(const u32x4*)&amaskw[m][nh * 16 + 4];
    u32x4 mv2 = *(const u32x4*)&amaskw[m][nh * 16 + 8];
    u32x4 mv3 = *(const u32x4*)&amaskw[m][nh * 16 + 12];
    // ---- pass A: masked row-max of s2 over this half; 8 independent chains ----
    float mxa0 = -3.0e38f, mxa1 = -3.0e38f, mxa2 = -3.0e38f, mxa3 = -3.0e38f;
    float mxa4 = -3.0e38f, mxa5 = -3.0e38f, mxa6 = -3.0e38f, mxa7 = -3.0e38f;
#pragma unroll
    for (int i = 0; i < 16; ++i) {
        unsigned word = (i < 4 ? mv0[i & 3] : i < 8 ? mv1[i & 3] : i < 12 ? mv2[i & 3]
                                                                          : mv3[i & 3]);
        unsigned wm8 = word >> (q * 8);
        int nn = nbase + i * 32 + q * 8;
        f32x4 svA = *(const f32x4*)&s2s[hd][nn];
        f32x4 svB = *(const f32x4*)&s2s[hd][nn + 4];
        mxa0 = fmaxf(mxa0, (wm8 & 1u)   ? svA[0] : -3.0e38f);
        mxa1 = fmaxf(mxa1, (wm8 & 2u)   ? svA[1] : -3.0e38f);
        mxa2 = fmaxf(mxa2, (wm8 & 4u)   ? svA[2] : -3.0e38f);
        mxa3 = fmaxf(mxa3, (wm8 & 8u)   ? svA[3] : -3.0e38f);
        mxa4 = fmaxf(mxa4, (wm8 & 16u)  ? svB[0] : -3.0e38f);
        mxa5 = fmaxf(mxa5, (wm8 & 32u)  ? svB[1] : -3.0e38f);
        mxa6 = fmaxf(mxa6, (wm8 & 64u)  ? svB[2] : -3.0e38f);
        mxa7 = fmaxf(mxa7, (wm8 & 128u) ? svB[3] : -3.0e38f);
    }
    float mxs2 = fmaxf(fmaxf(fmaxf(mxa0, mxa1), fmaxf(mxa2, mxa3)),
                       fmaxf(fmaxf(mxa4, mxa5), fmaxf(mxa6, mxa7)));
    mxs2 = fmaxf(mxs2, __shfl_xor(mxs2, 16));
    mxs2 = fmaxf(mxs2, __shfl_xor(mxs2, 32));   // masked max over this half, row m
    if (l < 16) mxsh[hd][l][nh] = mxs2;
    __syncthreads();
    float mxf = fmaxf(mxsh[hd][m][0], mxsh[hd][m][1]);   // full-row masked max
    float s1v = s1s[hd][m];
    float mxr = s1v + mxf;
    float mx = fmaxf(mxr, ALPHA * mxr);   // = leaky(best masked score): exact shift
    float c1 = s1v - mx;
    float c2 = fmaf(ALPHA, s1v, -mx);
    // ---- pass B: arg = bit ? leaky(score)-mx : -3e38 (arg<=0 masked-in: no inf,
    //      pv_max=1: rsum>=1, deterministically NaN-free) ----
    f32x4 acc0 = {0,0,0,0}, acc1 = {0,0,0,0}, accs = {0,0,0,0};
    s16x8 ones;
#pragma unroll
    for (int u = 0; u < 8; ++u) ones[u] = (short)0x3F80;   // bf16 1.0
    const unsigned short* bp0 = WhT + (b * 8 + h) * 32768 + m * 1024 + q * 8 + nbase;
    const unsigned short* bp1 = bp0 + 16 * 1024;
#pragma unroll
    for (int i = 0; i < 16; ++i) {
        int n0 = i * 32;
        unsigned word = (i < 4 ? mv0[i & 3] : i < 8 ? mv1[i & 3] : i < 12 ? mv2[i & 3]
                                                                          : mv3[i & 3]);
        unsigned wm8 = word >> (q * 8);
        int nn = nbase + n0 + q * 8;
        f32x4 svA = *(const f32x4*)&s2s[hd][nn];
        f32x4 svB = *(const f32x4*)&s2s[hd][nn + 4];
        float pv[8];
#pragma unroll
        for (int u = 0; u < 8; ++u) {
            float sv = (u < 4 ? svA[u] : svB[u - 4]);
            float arg = fmaxf(sv + c1, fmaf(ALPHA, sv, c2));     // leaky(score)-mx
            arg = ((wm8 >> u) & 1u) ? arg : -3.0e38f;            // select BEFORE exp
            pv[u] = __builtin_amdgcn_exp2f(arg);
        }
        u32x4 aw;
#pragma unroll
        for (int p = 0; p < 4; ++p) {
            union { float f; unsigned u; } lo, hi;
            lo.f = pv[2 * p]; hi.f = pv[2 * p + 1];
            aw[p] = __builtin_amdgcn_perm(hi.u, lo.u, 0x07060302u);  // trunc-pack 2xbf16
        }
        s16x8 af = __builtin_bit_cast(s16x8, aw);
        s16x8 bf0 = *(const s16x8*)(bp0 + n0);
        s16x8 bf1 = *(const s16x8*)(bp1 + n0);
        acc0 = __builtin_amdgcn_mfma_f32_16x16x32_bf16(af, bf0, acc0, 0, 0, 0);
        acc1 = __builtin_amdgcn_mfma_f32_16x16x32_bf16(af, bf1, acc1, 0, 0, 0);
        accs = __builtin_amdgcn_mfma_f32_16x16x32_bf16(af, ones, accs, 0, 0, 0);
    }
    if (nh == 1) {
#pragma unroll
        for (int j = 0; j < 4; ++j) {
            accsh[hd][l][j]     = acc0[j];
            accsh[hd][l][4 + j] = acc1[j];
            accsh[hd][l][8 + j] = accs[j];
        }
    }
    __syncthreads();
    if (nh == 0) {
#pragma unroll
        for (int j = 0; j < 4; ++j) {
            float a0 = acc0[j] + accsh[hd][l][j];
            float a1 = acc1[j] + accsh[hd][l][4 + j];
            float as = accs[j] + accsh[hd][l][8 + j];
            float inv = 1.f / as;
            float v0 = a0 * inv;
            float v1 = a1 * inv;
            v0 = v0 > 0.f ? v0 : __expf(v0) - 1.f;
            v1 = v1 > 0.f ? v1 : __expf(v1) - 1.f;
            int mrow = q * 4 + j;
            float* op = &out[(b * 1024 + m0 + mrow) * 256 + h * 32];
            op[m] = v0;
            op[16 + m] = v1;
        }
    }
}

extern "C" void kernel_launch(void* const* d_in, const int* in_sizes, int n_in,
                              void* d_out, int out_size, void* d_ws, size_t ws_size,
                              hipStream_t stream) {
    const float* x      = (const float*)d_in[0];
    const int*   adj    = (const int*)d_in[1];
    const float* weight = (const float*)d_in[2];
    const float* att    = (const float*)d_in[3];

    char* ws = (char*)d_ws;
    unsigned short* wT  = (unsigned short*)(ws);             // 128K
    unsigned short* x16 = (unsigned short*)(ws + 131072);    // 4M
    unsigned short* WhT = (unsigned short*)(ws + 4325376);   // 4M
    float* s1  = (float*)(ws + 8519680);                     // 256K
    float* s2  = (float*)(ws + 8781824);                     // 256K
    float* wa1 = (float*)(ws + 9043968);                     // 8K
    float* wa2 = (float*)(ws + 9052160);                     // 8K
    unsigned* gmask = (unsigned*)(ws + 9060352);             // 1M
    float* out = (float*)d_out;

    k_prep_w<<<272, 256, 0, stream>>>(weight, att, wT, wa1, wa2);
    k_pre<<<8192, 256, 0, stream>>>(adj, gmask, x, x16, wa1, wa2, s1, s2);
    k_wht<<<1024, 256, 0, stream>>>(wT, x16, WhT);
    k_attn<<<2048, 256, 0, stream>>>(gmask, s1, s2, WhT, out);
}

// Round 14
// 75.415 us; speedup vs baseline: 1.1297x; 1.0942x over previous
//
#include <hip/hip_runtime.h>
#include <stdint.h>

#define ALPHA 0.2f
#define LOG2E 1.44269504089f

typedef __attribute__((ext_vector_type(8))) short s16x8;
typedef __attribute__((ext_vector_type(4))) float f32x4;
typedef __attribute__((ext_vector_type(4))) unsigned u32x4;

__device__ __forceinline__ unsigned short f2bf(float f) {
    union { float f; unsigned u; } c; c.f = f;
    unsigned u = c.u;
    u += 0x7fffu + ((u >> 16) & 1u);
    return (unsigned short)(u >> 16);
}

// ---- prep: wT bf16 [c=256][f=256] (c=(h,e)) + wa1/wa2 = log2e * W@a{1,2} ----
__global__ void k_prep_w(const float* __restrict__ weight, const float* __restrict__ att,
                         unsigned short* __restrict__ wT, float* __restrict__ wa1,
                         float* __restrict__ wa2) {
    int blk = blockIdx.x, t = threadIdx.x;
    if (blk < 256) {
        int c = blk, h = c >> 5, e = c & 31;
        wT[c * 256 + t] = f2bf(weight[h * 8192 + t * 32 + e]);
    } else {
        int id = blk - 256, h = id >> 1, which = id & 1;
        float s = 0.f;
        for (int e = 0; e < 32; ++e)
            s += weight[h * 8192 + t * 32 + e] * att[h * 64 + which * 32 + e];
        s *= LOG2E;   // scores in log2 domain (leaky commutes with positive scale)
        (which ? wa2 : wa1)[h * 256 + t] = s;
    }
}

// ---- fused: adj staged to LDS -> ROW-MAJOR gmask words (r6-proven format),
//      x->bf16, s1/s2 dots. block = 16 adj rows; 512 threads ----
__global__ void __launch_bounds__(512) k_pre(const int* __restrict__ adj,
                                             unsigned* __restrict__ gmask,
                                             const float* __restrict__ x,
                                             unsigned short* __restrict__ x16,
                                             const float* __restrict__ wa1,
                                             const float* __restrict__ wa2,
                                             float* __restrict__ s1,
                                             float* __restrict__ s2) {
    __shared__ unsigned char adjb[16][1024];   // 0/1 bytes, col ^ ((row&7)<<4) swizzle
    __shared__ float xs[16][260];              // stride 260 (1040B, 16B-aligned rows)
    int blk = blockIdx.x;                      // blk = b*64 + mt
    int t = threadIdx.x, w = t >> 6, l = t & 63;
    const int* abase = adj + blk * 16384;
#pragma unroll
    for (int it = 0; it < 8; ++it) {
        int f = it * 512 + t;                  // int4 index in [0,4096)
        int4 v = *(const int4*)(abase + f * 4);
        int row = f >> 8, col = (f & 255) * 4;
        unsigned p1 = __builtin_amdgcn_perm((unsigned)v.y, (unsigned)v.x, 0x00000400u);
        unsigned p2 = __builtin_amdgcn_perm((unsigned)v.w, (unsigned)v.z, 0x00000400u);
        unsigned pk = __builtin_amdgcn_perm(p2, p1, 0x05040100u);  // (x0,y0,z0,w0)
        *(unsigned*)&adjb[row][col ^ ((row & 7) << 4)] = pk;
    }
    const float* xbase = x + blk * 4096;
#pragma unroll
    for (int it = 0; it < 2; ++it) {
        int f = it * 512 + t;                  // float4 index in [0,1024)
        float4 xv = *(const float4*)(xbase + f * 4);
        int row = f >> 6, col = (f & 63) * 4;
        *(float4*)&xs[row][col] = xv;
        ushort4 hv;
        hv.x = f2bf(xv.x); hv.y = f2bf(xv.y); hv.z = f2bf(xv.z); hv.w = f2bf(xv.w);
        *(ushort4*)&x16[blk * 4096 + f * 4] = hv;
    }
    __syncthreads();
    if (w < 4) {
        // row-major ballots: task = (row, 64-col chunk); bit l = adj(row, ch*64+l)
        for (int k = 0; k < 64; ++k) {
            int task = w * 64 + k;
            int row = task >> 4, ch = task & 15;
            unsigned char byv = adjb[row][(ch * 64 + l) ^ ((row & 7) << 4)];
            unsigned long long mk = __ballot(byv != 0);
            if (l == 0) {
                unsigned* dst = gmask + (blk * 16 + row) * 32 + ch * 2;
                dst[0] = (unsigned)mk;
                dst[1] = (unsigned)(mk >> 32);
            }
        }
    } else {
        // s1/s2 dots (256 dots of length 256)
        int td = (w - 4) * 64 + l;
        int row = td & 15, grp = td >> 4;
        int h = grp >> 1, which = grp & 1;
        const float* wap = (which ? wa2 : wa1) + h * 256;
        float s = 0.f;
#pragma unroll 4
        for (int f = 0; f < 256; f += 4) {
            f32x4 xv = *(const f32x4*)&xs[row][f];
            f32x4 wv = *(const f32x4*)&wap[f];
            s += xv[0] * wv[0] + xv[1] * wv[1] + xv[2] * wv[2] + xv[3] * wv[3];
        }
        int b = blk >> 6, m = (blk & 63) * 16 + row;
        (which ? s2 : s1)[(b * 8 + h) * 1024 + m] = s;
    }
}

// ---- WhT[(b,h,e)][m] bf16 = (x@W)^T via MFMA; BM=32 tiles ----
__global__ void k_wht(const unsigned short* __restrict__ wT,
                      const unsigned short* __restrict__ x16,
                      unsigned short* __restrict__ WhT) {
    int t = threadIdx.x;
    int W = blockIdx.x * 4 + (t >> 6);
    int l = t & 63;
    int b = W >> 9, r = W & 511;
    int c0 = (r >> 5) * 16, m0 = (r & 31) * 32;
    int lrow = l & 15, lk = l >> 4;
    f32x4 acc[2] = {{0,0,0,0},{0,0,0,0}};
    const unsigned short* ap = wT + (c0 + lrow) * 256 + lk * 8;
    const unsigned short* bp = x16 + (b * 1024 + m0 + lrow) * 256 + lk * 8;
    for (int k0 = 0; k0 < 256; k0 += 32) {
        s16x8 af = *(const s16x8*)(ap + k0);
#pragma unroll
        for (int t4 = 0; t4 < 2; ++t4) {
            s16x8 bf = *(const s16x8*)(bp + t4 * 16 * 256 + k0);
            acc[t4] = __builtin_amdgcn_mfma_f32_16x16x32_bf16(af, bf, acc[t4], 0, 0, 0);
        }
    }
#pragma unroll
    for (int t4 = 0; t4 < 2; ++t4)
#pragma unroll
        for (int j = 0; j < 4; ++j) {
            int c = c0 + lk * 4 + j;
            int m = m0 + t4 * 16 + lrow;
            WhT[(b * 256 + c) * 1024 + m] = f2bf(acc[t4][j]);
        }
}

// ---- attention: VERBATIM round-11-passed kernel (exact masked row-max,
//      register mask words, select-before-exp) ----
__global__ void __launch_bounds__(256, 4) k_attn(const unsigned* __restrict__ gmask,
                                                 const float* __restrict__ s1,
                                                 const float* __restrict__ s2,
                                                 const unsigned short* __restrict__ WhT,
                                                 float* __restrict__ out) {
    __shared__ float s2s[2][1024];
    __shared__ unsigned amaskw[16][36];   // rows 144B: 16B-aligned, 2-way-free banks
    __shared__ float s1s[2][16];
    __shared__ float mxsh[2][16][2];
    __shared__ float accsh[2][64][13];
    int bid = blockIdx.x;
    int o = (bid & 7) * 256 + (bid >> 3);   // XCD swizzle: each XCD owns one b
    int b = o >> 8, r = o & 255;
    int m0 = (r >> 2) * 16, hg = (r & 3) * 2;
    int t = threadIdx.x, w = t >> 6, l = t & 63;
    int hd = w & 1, nh = w >> 1;
    for (int i = t; i < 2048; i += 256) s2s[i >> 10][i & 1023] = s2[b * 8192 + hg * 1024 + i];
    for (int i = t; i < 512; i += 256) amaskw[i >> 5][i & 31] = gmask[(b * 1024 + m0) * 32 + i];
    if (t < 32) s1s[t >> 4][t & 15] = s1[b * 8192 + (hg + (t >> 4)) * 1024 + m0 + (t & 15)];
    __syncthreads();
    int m = l & 15, q = l >> 4;
    int h = hg + hd;
    int nbase = nh * 512;
    u32x4 mv0 = *(const u32x4*)&amaskw[m][nh * 16];
    u32x4 mv1 = *(const u32x4*)&amaskw[m][nh * 16 + 4];
    u32x4 mv2 = *(const u32x4*)&amaskw[m][nh * 16 + 8];
    u32x4 mv3 = *(const u32x4*)&amaskw[m][nh * 16 + 12];
    // ---- pass A: masked row-max of s2 over this half; 8 independent chains ----
    float mxa0 = -3.0e38f, mxa1 = -3.0e38f, mxa2 = -3.0e38f, mxa3 = -3.0e38f;
    float mxa4 = -3.0e38f, mxa5 = -3.0e38f, mxa6 = -3.0e38f, mxa7 = -3.0e38f;
#pragma unroll
    for (int i = 0; i < 16; ++i) {
        unsigned word = (i < 4 ? mv0[i & 3] : i < 8 ? mv1[i & 3] : i < 12 ? mv2[i & 3]
                                                                          : mv3[i & 3]);
        unsigned wm8 = word >> (q * 8);
        int nn = nbase + i * 32 + q * 8;
        f32x4 svA = *(const f32x4*)&s2s[hd][nn];
        f32x4 svB = *(const f32x4*)&s2s[hd][nn + 4];
        mxa0 = fmaxf(mxa0, (wm8 & 1u)   ? svA[0] : -3.0e38f);
        mxa1 = fmaxf(mxa1, (wm8 & 2u)   ? svA[1] : -3.0e38f);
        mxa2 = fmaxf(mxa2, (wm8 & 4u)   ? svA[2] : -3.0e38f);
        mxa3 = fmaxf(mxa3, (wm8 & 8u)   ? svA[3] : -3.0e38f);
        mxa4 = fmaxf(mxa4, (wm8 & 16u)  ? svB[0] : -3.0e38f);
        mxa5 = fmaxf(mxa5, (wm8 & 32u)  ? svB[1] : -3.0e38f);
        mxa6 = fmaxf(mxa6, (wm8 & 64u)  ? svB[2] : -3.0e38f);
        mxa7 = fmaxf(mxa7, (wm8 & 128u) ? svB[3] : -3.0e38f);
    }
    float mxs2 = fmaxf(fmaxf(fmaxf(mxa0, mxa1), fmaxf(mxa2, mxa3)),
                       fmaxf(fmaxf(mxa4, mxa5), fmaxf(mxa6, mxa7)));
    mxs2 = fmaxf(mxs2, __shfl_xor(mxs2, 16));
    mxs2 = fmaxf(mxs2, __shfl_xor(mxs2, 32));   // masked max over this half, row m
    if (l < 16) mxsh[hd][l][nh] = mxs2;
    __syncthreads();
    float mxf = fmaxf(mxsh[hd][m][0], mxsh[hd][m][1]);   // full-row masked max
    float s1v = s1s[hd][m];
    float mxr = s1v + mxf;
    float mx = fmaxf(mxr, ALPHA * mxr);   // = leaky(best masked score): exact shift
    float c1 = s1v - mx;
    float c2 = fmaf(ALPHA, s1v, -mx);
    // ---- pass B: arg = bit ? leaky(score)-mx : -3e38 (select BEFORE exp) ----
    f32x4 acc0 = {0,0,0,0}, acc1 = {0,0,0,0}, accs = {0,0,0,0};
    s16x8 ones;
#pragma unroll
    for (int u = 0; u < 8; ++u) ones[u] = (short)0x3F80;   // bf16 1.0
    const unsigned short* bp0 = WhT + (b * 8 + h) * 32768 + m * 1024 + q * 8 + nbase;
    const unsigned short* bp1 = bp0 + 16 * 1024;
#pragma unroll
    for (int i = 0; i < 16; ++i) {
        int n0 = i * 32;
        unsigned word = (i < 4 ? mv0[i & 3] : i < 8 ? mv1[i & 3] : i < 12 ? mv2[i & 3]
                                                                          : mv3[i & 3]);
        unsigned wm8 = word >> (q * 8);
        int nn = nbase + n0 + q * 8;
        f32x4 svA = *(const f32x4*)&s2s[hd][nn];
        f32x4 svB = *(const f32x4*)&s2s[hd][nn + 4];
        float pv[8];
#pragma unroll
        for (int u = 0; u < 8; ++u) {
            float sv = (u < 4 ? svA[u] : svB[u - 4]);
            float arg = fmaxf(sv + c1, fmaf(ALPHA, sv, c2));     // leaky(score)-mx
            arg = ((wm8 >> u) & 1u) ? arg : -3.0e38f;            // select BEFORE exp
            pv[u] = __builtin_amdgcn_exp2f(arg);
        }
        u32x4 aw;
#pragma unroll
        for (int p = 0; p < 4; ++p) {
            union { float f; unsigned u; } lo, hi;
            lo.f = pv[2 * p]; hi.f = pv[2 * p + 1];
            aw[p] = __builtin_amdgcn_perm(hi.u, lo.u, 0x07060302u);  // trunc-pack 2xbf16
        }
        s16x8 af = __builtin_bit_cast(s16x8, aw);
        s16x8 bf0 = *(const s16x8*)(bp0 + n0);
        s16x8 bf1 = *(const s16x8*)(bp1 + n0);
        acc0 = __builtin_amdgcn_mfma_f32_16x16x32_bf16(af, bf0, acc0, 0, 0, 0);
        acc1 = __builtin_amdgcn_mfma_f32_16x16x32_bf16(af, bf1, acc1, 0, 0, 0);
        accs = __builtin_amdgcn_mfma_f32_16x16x32_bf16(af, ones, accs, 0, 0, 0);
    }
    if (nh == 1) {
#pragma unroll
        for (int j = 0; j < 4; ++j) {
            accsh[hd][l][j]     = acc0[j];
            accsh[hd][l][4 + j] = acc1[j];
            accsh[hd][l][8 + j] = accs[j];
        }
    }
    __syncthreads();
    if (nh == 0) {
#pragma unroll
        for (int j = 0; j < 4; ++j) {
            float a0 = acc0[j] + accsh[hd][l][j];
            float a1 = acc1[j] + accsh[hd][l][4 + j];
            float as = accs[j] + accsh[hd][l][8 + j];
            float inv = 1.f / as;
            float v0 = a0 * inv;
            float v1 = a1 * inv;
            v0 = v0 > 0.f ? v0 : __expf(v0) - 1.f;
            v1 = v1 > 0.f ? v1 : __expf(v1) - 1.f;
            int mrow = q * 4 + j;
            float* op = &out[(b * 1024 + m0 + mrow) * 256 + h * 32];
            op[m] = v0;
            op[16 + m] = v1;
        }
    }
}

extern "C" void kernel_launch(void* const* d_in, const int* in_sizes, int n_in,
                              void* d_out, int out_size, void* d_ws, size_t ws_size,
                              hipStream_t stream) {
    const float* x      = (const float*)d_in[0];
    const int*   adj    = (const int*)d_in[1];
    const float* weight = (const float*)d_in[2];
    const float* att    = (const float*)d_in[3];

    char* ws = (char*)d_ws;
    unsigned short* wT  = (unsigned short*)(ws);             // 128K
    unsigned short* x16 = (unsigned short*)(ws + 131072);    // 4M
    unsigned short* WhT = (unsigned short*)(ws + 4325376);   // 4M
    float* s1  = (float*)(ws + 8519680);                     // 256K
    float* s2  = (float*)(ws + 8781824);                     // 256K
    float* wa1 = (float*)(ws + 9043968);                     // 8K
    float* wa2 = (float*)(ws + 9052160);                     // 8K
    unsigned* gmask = (unsigned*)(ws + 9060352);             // 1M
    float* out = (float*)d_out;

    k_prep_w<<<272, 256, 0, stream>>>(weight, att, wT, wa1, wa2);
    k_pre<<<512, 512, 0, stream>>>(adj, gmask, x, x16, wa1, wa2, s1, s2);
    k_wht<<<1024, 256, 0, stream>>>(wT, x16, WhT);
    k_attn<<<2048, 256, 0, stream>>>(gmask, s1, s2, WhT, out);
}

// Round 15
// 68.803 us; speedup vs baseline: 1.2383x; 1.0961x over previous
//
#include <hip/hip_runtime.h>
#include <stdint.h>

#define ALPHA 0.2f
#define LOG2E 1.44269504089f

typedef __attribute__((ext_vector_type(8))) short s16x8;
typedef __attribute__((ext_vector_type(4))) float f32x4;
typedef __attribute__((ext_vector_type(4))) unsigned u32x4;

__device__ __forceinline__ unsigned short f2bf(float f) {
    union { float f; unsigned u; } c; c.f = f;
    unsigned u = c.u;
    u += 0x7fffu + ((u >> 16) & 1u);
    return (unsigned short)(u >> 16);
}

// ---- prep: wT bf16 [c=256][f=256] (c=(h,e)) + wa1/wa2 = log2e * W@a{1,2} ----
__global__ void k_prep_w(const float* __restrict__ weight, const float* __restrict__ att,
                         unsigned short* __restrict__ wT, float* __restrict__ wa1,
                         float* __restrict__ wa2) {
    int blk = blockIdx.x, t = threadIdx.x;
    if (blk < 256) {
        int c = blk, h = c >> 5, e = c & 31;
        wT[c * 256 + t] = f2bf(weight[h * 8192 + t * 32 + e]);
    } else {
        int id = blk - 256, h = id >> 1, which = id & 1;
        float s = 0.f;
        for (int e = 0; e < 32; ++e)
            s += weight[h * 8192 + t * 32 + e] * att[h * 64 + which * 32 + e];
        s *= LOG2E;   // scores in log2 domain (leaky commutes with positive scale)
        (which ? wa2 : wa1)[h * 256 + t] = s;
    }
}

// ---- fused: adj->gmask ballots, x->LDS, s1/s2 dots, AND Wh^T MFMA ----
// block = 16 rows; 512 threads (8 waves); 3 kernels total in the chain
__global__ void __launch_bounds__(512) k_pre(const int* __restrict__ adj,
                                             unsigned* __restrict__ gmask,
                                             const float* __restrict__ x,
                                             const unsigned short* __restrict__ wT,
                                             const float* __restrict__ wa1,
                                             const float* __restrict__ wa2,
                                             float* __restrict__ s1,
                                             float* __restrict__ s2,
                                             unsigned short* __restrict__ WhT) {
    __shared__ unsigned char adjb[16][1024];   // 0/1 bytes, col ^ ((row&7)<<4) swizzle
    __shared__ float xs[16][260];              // fp32 rows (dots), padded
    __shared__ unsigned short x16s[16][256];   // bf16 rows, 16B-unit XOR swizzle (MFMA B)
    int blk = blockIdx.x;                      // blk = b*64 + mt
    int t = threadIdx.x, w = t >> 6, l = t & 63;
    int b = blk >> 6;
    // phase 1a: adj block -> 0/1 bytes in LDS
    const int* abase = adj + blk * 16384;
#pragma unroll
    for (int it = 0; it < 8; ++it) {
        int f = it * 512 + t;                  // int4 index in [0,4096)
        int4 v = *(const int4*)(abase + f * 4);
        int row = f >> 8, col = (f & 255) * 4;
        unsigned p1 = __builtin_amdgcn_perm((unsigned)v.y, (unsigned)v.x, 0x00000400u);
        unsigned p2 = __builtin_amdgcn_perm((unsigned)v.w, (unsigned)v.z, 0x00000400u);
        unsigned pk = __builtin_amdgcn_perm(p2, p1, 0x05040100u);  // (x0,y0,z0,w0)
        *(unsigned*)&adjb[row][col ^ ((row & 7) << 4)] = pk;
    }
    // phase 1b: stage x rows fp32 + swizzled bf16 copy (LDS only)
    const float* xbase = x + blk * 4096;
#pragma unroll
    for (int it = 0; it < 2; ++it) {
        int f = it * 512 + t;                  // float4 index in [0,1024)
        float4 xv = *(const float4*)(xbase + f * 4);
        int row = f >> 6, col = (f & 63) * 4;
        *(float4*)&xs[row][col] = xv;
        ushort4 hv;
        hv.x = f2bf(xv.x); hv.y = f2bf(xv.y); hv.z = f2bf(xv.z); hv.w = f2bf(xv.w);
        *(ushort4*)((char*)&x16s[0][0] + ((row * 512 + col * 2) ^ ((row & 7) << 4))) = hv;
    }
    __syncthreads();
    if (w < 4) {
        // phase 2a: row-major ballots (r14-proven)
        for (int k = 0; k < 64; ++k) {
            int task = w * 64 + k;
            int row = task >> 4, ch = task & 15;
            unsigned char byv = adjb[row][(ch * 64 + l) ^ ((row & 7) << 4)];
            unsigned long long mk = __ballot(byv != 0);
            if (l == 0) {
                unsigned* dst = gmask + (blk * 16 + row) * 32 + ch * 2;
                dst[0] = (unsigned)mk;
                dst[1] = (unsigned)(mk >> 32);
            }
        }
    } else {
        // phase 2b: s1/s2 dots (256 dots of length 256)
        int td = (w - 4) * 64 + l;
        int row = td & 15, grp = td >> 4;
        int h = grp >> 1, which = grp & 1;
        const float* wap = (which ? wa2 : wa1) + h * 256;
        float s = 0.f;
#pragma unroll 4
        for (int f = 0; f < 256; f += 4) {
            f32x4 xv = *(const f32x4*)&xs[row][f];
            f32x4 wv = *(const f32x4*)&wap[f];
            s += xv[0] * wv[0] + xv[1] * wv[1] + xv[2] * wv[2] + xv[3] * wv[3];
        }
        int m = (blk & 63) * 16 + row;
        (which ? s2 : s1)[(b * 8 + h) * 1024 + m] = s;
    }
    // phase 3: Wh^T for this 16-row tile; 16 c-tiles over 8 waves (2 each)
    int lrow = l & 15, lk = l >> 4;
#pragma unroll
    for (int ct = 0; ct < 2; ++ct) {
        int c0 = (w * 2 + ct) * 16;
        f32x4 acc = {0, 0, 0, 0};
        const unsigned short* ap = wT + (c0 + lrow) * 256 + lk * 8;
#pragma unroll
        for (int k0 = 0; k0 < 256; k0 += 32) {
            s16x8 af = *(const s16x8*)(ap + k0);
            s16x8 bf = *(const s16x8*)((char*)&x16s[0][0] +
                        ((lrow * 512 + (lk * 8 + k0) * 2) ^ ((lrow & 7) << 4)));
            acc = __builtin_amdgcn_mfma_f32_16x16x32_bf16(af, bf, acc, 0, 0, 0);
        }
#pragma unroll
        for (int j = 0; j < 4; ++j) {
            int c = c0 + lk * 4 + j;               // D row = (h,e) index
            WhT[(b * 256 + c) * 1024 + (blk & 63) * 16 + lrow] = f2bf(acc[j]);
        }
    }
}

// ---- attention: 1024 blocks x 512 thr; 8 waves = 4 heads x 2 n-halves;
//      exact masked row-max (max3 chains) + select-before-exp pass B ----
__global__ void __launch_bounds__(512, 4) k_attn(const unsigned* __restrict__ gmask,
                                                 const float* __restrict__ s1,
                                                 const float* __restrict__ s2,
                                                 const unsigned short* __restrict__ WhT,
                                                 float* __restrict__ out) {
    __shared__ float s2s[4][1024];
    __shared__ unsigned amaskw[16][36];
    __shared__ float s1s[4][16];
    __shared__ float mxsh[4][16][2];
    __shared__ float accsh[4][64][13];
    int bid = blockIdx.x;
    int o = (bid & 7) * 128 + (bid >> 3);   // XCD swizzle: each XCD owns one b
    int b = o >> 7, r = o & 127;
    int mt = r >> 1, m0 = mt * 16, hg = (r & 1) * 4;
    int t = threadIdx.x, w = t >> 6, l = t & 63;
    int hd = w & 3, nh = w >> 2;
    for (int i = t; i < 4096; i += 512)
        s2s[i >> 10][i & 1023] = s2[b * 8192 + hg * 1024 + i];
    amaskw[t >> 5][t & 31] = gmask[(b * 1024 + m0) * 32 + t];
    if (t < 64) s1s[t >> 4][t & 15] = s1[b * 8192 + (hg + (t >> 4)) * 1024 + m0 + (t & 15)];
    __syncthreads();
    int m = l & 15, q = l >> 4;
    int h = hg + hd;
    int nbase = nh * 512;
    u32x4 mv0 = *(const u32x4*)&amaskw[m][nh * 16];
    u32x4 mv1 = *(const u32x4*)&amaskw[m][nh * 16 + 4];
    u32x4 mv2 = *(const u32x4*)&amaskw[m][nh * 16 + 8];
    u32x4 mv3 = *(const u32x4*)&amaskw[m][nh * 16 + 12];
    // ---- pass A: masked row-max; 4 max3-fusable chains ----
    float mx01 = -3.0e38f, mx23 = -3.0e38f, mx45 = -3.0e38f, mx67 = -3.0e38f;
#pragma unroll
    for (int i = 0; i < 16; ++i) {
        unsigned word = (i < 4 ? mv0[i & 3] : i < 8 ? mv1[i & 3] : i < 12 ? mv2[i & 3]
                                                                          : mv3[i & 3]);
        unsigned wm8 = word >> (q * 8);
        int nn = nbase + i * 32 + q * 8;
        f32x4 svA = *(const f32x4*)&s2s[hd][nn];
        f32x4 svB = *(const f32x4*)&s2s[hd][nn + 4];
        float c0 = (wm8 & 1u)   ? svA[0] : -3.0e38f;
        float c1 = (wm8 & 2u)   ? svA[1] : -3.0e38f;
        float c2 = (wm8 & 4u)   ? svA[2] : -3.0e38f;
        float c3 = (wm8 & 8u)   ? svA[3] : -3.0e38f;
        float c4 = (wm8 & 16u)  ? svB[0] : -3.0e38f;
        float c5 = (wm8 & 32u)  ? svB[1] : -3.0e38f;
        float c6 = (wm8 & 64u)  ? svB[2] : -3.0e38f;
        float c7 = (wm8 & 128u) ? svB[3] : -3.0e38f;
        mx01 = fmaxf(mx01, fmaxf(c0, c1));   // v_max3
        mx23 = fmaxf(mx23, fmaxf(c2, c3));
        mx45 = fmaxf(mx45, fmaxf(c4, c5));
        mx67 = fmaxf(mx67, fmaxf(c6, c7));
    }
    float mxs2 = fmaxf(fmaxf(mx01, mx23), fmaxf(mx45, mx67));
    mxs2 = fmaxf(mxs2, __shfl_xor(mxs2, 16));
    mxs2 = fmaxf(mxs2, __shfl_xor(mxs2, 32));   // masked max over this half, row m
    if (l < 16) mxsh[hd][l][nh] = mxs2;
    __syncthreads();
    float mxf = fmaxf(mxsh[hd][m][0], mxsh[hd][m][1]);   // full-row masked max
    float s1v = s1s[hd][m];
    float mxr = s1v + mxf;
    float mx = fmaxf(mxr, ALPHA * mxr);   // = leaky(best masked score): exact shift
    float cc1 = s1v - mx;
    float cc2 = fmaf(ALPHA, s1v, -mx);
    // ---- pass B: arg = bit ? leaky(score)-mx : -3e38 (select BEFORE exp) ----
    f32x4 acc0 = {0,0,0,0}, acc1 = {0,0,0,0}, accs = {0,0,0,0};
    s16x8 ones;
#pragma unroll
    for (int u = 0; u < 8; ++u) ones[u] = (short)0x3F80;   // bf16 1.0
    const unsigned short* bp0 = WhT + (b * 8 + h) * 32768 + m * 1024 + q * 8 + nbase;
    const unsigned short* bp1 = bp0 + 16 * 1024;
#pragma unroll
    for (int i = 0; i < 16; ++i) {
        int n0 = i * 32;
        unsigned word = (i < 4 ? mv0[i & 3] : i < 8 ? mv1[i & 3] : i < 12 ? mv2[i & 3]
                                                                          : mv3[i & 3]);
        unsigned wm8 = word >> (q * 8);
        int nn = nbase + n0 + q * 8;
        f32x4 svA = *(const f32x4*)&s2s[hd][nn];
        f32x4 svB = *(const f32x4*)&s2s[hd][nn + 4];
        float pv[8];
#pragma unroll
        for (int u = 0; u < 8; ++u) {
            float sv = (u < 4 ? svA[u] : svB[u - 4]);
            float arg = fmaxf(sv + cc1, fmaf(ALPHA, sv, cc2));   // leaky(score)-mx
            arg = ((wm8 >> u) & 1u) ? arg : -3.0e38f;            // select BEFORE exp
            pv[u] = __builtin_amdgcn_exp2f(arg);
        }
        u32x4 aw;
#pragma unroll
        for (int p = 0; p < 4; ++p) {
            union { float f; unsigned u; } lo, hi;
            lo.f = pv[2 * p]; hi.f = pv[2 * p + 1];
            aw[p] = __builtin_amdgcn_perm(hi.u, lo.u, 0x07060302u);  // trunc-pack 2xbf16
        }
        s16x8 af = __builtin_bit_cast(s16x8, aw);
        s16x8 bf0 = *(const s16x8*)(bp0 + n0);
        s16x8 bf1 = *(const s16x8*)(bp1 + n0);
        acc0 = __builtin_amdgcn_mfma_f32_16x16x32_bf16(af, bf0, acc0, 0, 0, 0);
        acc1 = __builtin_amdgcn_mfma_f32_16x16x32_bf16(af, bf1, acc1, 0, 0, 0);
        accs = __builtin_amdgcn_mfma_f32_16x16x32_bf16(af, ones, accs, 0, 0, 0);
    }
    if (nh == 1) {
#pragma unroll
        for (int j = 0; j < 4; ++j) {
            accsh[hd][l][j]     = acc0[j];
            accsh[hd][l][4 + j] = acc1[j];
            accsh[hd][l][8 + j] = accs[j];
        }
    }
    __syncthreads();
    if (nh == 0) {
#pragma unroll
        for (int j = 0; j < 4; ++j) {
            float a0 = acc0[j] + accsh[hd][l][j];
            float a1 = acc1[j] + accsh[hd][l][4 + j];
            float as = accs[j] + accsh[hd][l][8 + j];
            float inv = 1.f / as;
            float v0 = a0 * inv;
            float v1 = a1 * inv;
            v0 = v0 > 0.f ? v0 : __expf(v0) - 1.f;
            v1 = v1 > 0.f ? v1 : __expf(v1) - 1.f;
            int mrow = q * 4 + j;
            float* op = &out[(b * 1024 + m0 + mrow) * 256 + h * 32];
            op[m] = v0;
            op[16 + m] = v1;
        }
    }
}

extern "C" void kernel_launch(void* const* d_in, const int* in_sizes, int n_in,
                              void* d_out, int out_size, void* d_ws, size_t ws_size,
                              hipStream_t stream) {
    const float* x      = (const float*)d_in[0];
    const int*   adj    = (const int*)d_in[1];
    const float* weight = (const float*)d_in[2];
    const float* att    = (const float*)d_in[3];

    char* ws = (char*)d_ws;
    unsigned short* wT  = (unsigned short*)(ws);             // 128K
    unsigned short* WhT = (unsigned short*)(ws + 131072);    // 4M
    float* s1  = (float*)(ws + 4325376);                     // 256K
    float* s2  = (float*)(ws + 4587520);                     // 256K
    float* wa1 = (float*)(ws + 4849664);                     // 8K
    float* wa2 = (float*)(ws + 4857856);                     // 8K
    unsigned* gmask = (unsigned*)(ws + 4866048);             // 1M (end ~5.9MB)
    float* out = (float*)d_out;

    k_prep_w<<<272, 256, 0, stream>>>(weight, att, wT, wa1, wa2);
    k_pre<<<512, 512, 0, stream>>>(adj, gmask, x, wT, wa1, wa2, s1, s2, WhT);
    k_attn<<<1024, 512, 0, stream>>>(gmask, s1, s2, WhT, out);
}